// Round 8
// baseline (35.585 us; speedup 1.0000x reference)
//
#include <hip/hip_runtime.h>
#include <hip/hip_bf16.h>

#define ALPHA 0.2f
#define NEGINF -9000000000000000.0f

typedef __attribute__((ext_vector_type(8))) short short8;
typedef __attribute__((ext_vector_type(4))) float f32x4;
typedef __attribute__((ext_vector_type(4))) unsigned short u16x4;

static constexpr int NB = 4, NN = 1024, NF = 256, NH = 32;

__device__ __forceinline__ unsigned short f2bf(float x) {
  union { float f; unsigned u; } v; v.f = x;
  unsigned r = v.u + 0x7fffu + ((v.u >> 16) & 1u);
  return (unsigned short)(r >> 16);
}

// ---- Kernel A: wa1 = W@a1, wa2 = W@a2, W transpose-packed bf16 ----
// WTp layout: 16B chunk (kc, f) holds W[kc*8+s][f], s=0..7 (B-frag = 16B/lane)
__global__ __launch_bounds__(256) void prep_kernel(
    const float* __restrict__ W, const float* __restrict__ a,
    float* __restrict__ wa1, float* __restrict__ wa2,
    unsigned short* __restrict__ WTp) {
  int k = blockIdx.x;     // 0..255 (row of W)
  int t = threadIdx.x;    // 0..255 (col of W)
  float w = W[k * NF + t];
  WTp[(((k >> 3) * NF) + t) * 8 + (k & 7)] = f2bf(w);
  float p1 = w * a[t];
  float p2 = w * a[NF + t];
#pragma unroll
  for (int off = 32; off >= 1; off >>= 1) {
    p1 += __shfl_xor(p1, off);
    p2 += __shfl_xor(p2, off);
  }
  __shared__ float r1[4], r2[4];
  if ((t & 63) == 0) { r1[t >> 6] = p1; r2[t >> 6] = p2; }
  __syncthreads();
  if (t == 0) {
    wa1[k] = r1[0] + r1[1] + r1[2] + r1[3];
    wa2[k] = r2[0] + r2[1] + r2[2] + r2[3];
  }
}

// ---- Kernel B: Wh = h@W (bf16 MFMA) + s1/s2 + adj->bitmask pack ----
// WhP layout per batch: 16B chunk (jc, f) holds Wh[jc*8+s][f]
// adjm[(b*NN+row)*16 + seg] = 64-bit mask of adj[b][row][seg*64..seg*64+63]>0
__global__ __launch_bounds__(512) void wh_kernel(
    const float* __restrict__ h, const unsigned short* __restrict__ WTp,
    const float* __restrict__ wa1, const float* __restrict__ wa2,
    const int* __restrict__ adj, unsigned short* __restrict__ WhP,
    float* __restrict__ s1g, float* __restrict__ s2g,
    unsigned long long* __restrict__ adjm) {
  __shared__ unsigned short hs[16 * 256];  // 8KB, XOR-swizzled
  int bid = blockIdx.x;
  int b = bid >> 6;
  int rb = (bid & 63) << 4;  // 16-row tile base within batch
  int t = threadIdx.x;
  int wid = t >> 6, lane = t & 63;

  // issue this block's adj loads FIRST: 16 rows x 16 segs, in flight during
  // the h-stage + MFMA below. wave wid owns rows wid*2, wid*2+1 (16 segs each)
  int av[32];
  {
    const int* adjb = adj + ((size_t)(b * NN + rb)) * NN;
#pragma unroll
    for (int i = 0; i < 32; ++i) {
      int p = wid * 32 + i;            // row = p>>4, seg = p&15
      av[i] = adjb[(size_t)(p >> 4) * NN + (p & 15) * 64 + lane];
    }
  }

  {
    int row = t >> 5, c0 = (t & 31) * 8;
    const float* src = h + (size_t)(b * NN + rb + row) * NF + c0;
    f32x4 v0 = *(const f32x4*)src;
    f32x4 v1 = *(const f32x4*)(src + 4);
    unsigned short tmp[8] = {f2bf(v0.x), f2bf(v0.y), f2bf(v0.z), f2bf(v0.w),
                             f2bf(v1.x), f2bf(v1.y), f2bf(v1.z), f2bf(v1.w)};
    int off = row * 512 + ((c0 * 2) ^ ((row & 7) << 4));
    *(short8*)((char*)hs + off) = *(const short8*)tmp;
    f32x4 a10 = *(const f32x4*)(wa1 + c0);
    f32x4 a11 = *(const f32x4*)(wa1 + c0 + 4);
    f32x4 a20 = *(const f32x4*)(wa2 + c0);
    f32x4 a21 = *(const f32x4*)(wa2 + c0 + 4);
    float d1 = v0.x * a10.x + v0.y * a10.y + v0.z * a10.z + v0.w * a10.w +
               v1.x * a11.x + v1.y * a11.y + v1.z * a11.z + v1.w * a11.w;
    float d2 = v0.x * a20.x + v0.y * a20.y + v0.z * a20.z + v0.w * a20.w +
               v1.x * a21.x + v1.y * a21.y + v1.z * a21.z + v1.w * a21.w;
#pragma unroll
    for (int off2 = 16; off2 >= 1; off2 >>= 1) {
      d1 += __shfl_xor(d1, off2);
      d2 += __shfl_xor(d2, off2);
    }
    if ((t & 31) == 0) {
      s1g[b * NN + rb + row] = d1;
      s2g[b * NN + rb + row] = d2;
    }
  }
  __syncthreads();
  {
    int fb = wid * 32;
    int rowa = lane & 15, kg = lane >> 4;
    f32x4 acc0 = {0.f, 0.f, 0.f, 0.f}, acc1 = {0.f, 0.f, 0.f, 0.f};
#pragma unroll
    for (int ks = 0; ks < 8; ++ks) {
      int k0 = ks * 32;
      short8 af = *(const short8*)((const char*)hs + rowa * 512 +
                                   ((2 * (k0 + kg * 8)) ^ ((rowa & 7) << 4)));
      int kc = ks * 4 + kg;
      short8 bf0 = *(const short8*)(WTp + ((kc * NF) + fb + (lane & 15)) * 8);
      short8 bf1 = *(const short8*)(WTp + ((kc * NF) + fb + 16 + (lane & 15)) * 8);
      acc0 = __builtin_amdgcn_mfma_f32_16x16x32_bf16(af, bf0, acc0, 0, 0, 0);
      acc1 = __builtin_amdgcn_mfma_f32_16x16x32_bf16(af, bf1, acc1, 0, 0, 0);
    }
#pragma unroll
    for (int r = 0; r < 4; ++r) {
      int jl = (lane >> 4) * 4 + r;  // C/D layout: row=(lane>>4)*4+reg
      int j = rb + jl;
      int base = ((b << 7) + (j >> 3)) * NF;
      WhP[(size_t)(base + fb + (lane & 15)) * 8 + (j & 7)] = f2bf(acc0[r]);
      WhP[(size_t)(base + fb + 16 + (lane & 15)) * 8 + (j & 7)] = f2bf(acc1[r]);
    }
  }

  // compress adj -> bitmask (loads landed during the GEMM above)
  {
#pragma unroll
    for (int i = 0; i < 32; ++i) {
      unsigned long long m = __ballot(av[i] > 0);
      int p = wid * 32 + i;
      if (lane == 0)
        adjm[(size_t)(b * NN + rb + (p >> 4)) * 16 + (p & 15)] = m;
    }
  }
}

// ---- Kernel C: scores + softmax + PV + ELU ----
// 128 blocks x 1024 threads (16 waves), 32 rows per block; adjacency comes
// from the packed bitmask (4KB/block from L2) instead of 128KB of int32.
__global__ __launch_bounds__(1024) void attn_kernel(
    const float* __restrict__ mz, const unsigned long long* __restrict__ adjm,
    const unsigned short* __restrict__ WhP,
    const float* __restrict__ w1, const float* __restrict__ b1,
    const float* __restrict__ w2, const float* __restrict__ b2,
    const float* __restrict__ s1g, const float* __restrict__ s2g,
    float* __restrict__ out) {
  __shared__ unsigned short Pb[32 * 1024];  // 64KB XOR-swizzled bf16 P
  __shared__ unsigned long long adjmsh[32][16];  // 4KB bitmask
  __shared__ float mzs[1024];
  __shared__ float s2s[1024];
  __shared__ float s1s[32];
  __shared__ float rinv[32];
  __shared__ float segsh[3];

  int bid0 = blockIdx.x;  // 0..127
  // XCD-aware bijective swizzle (nwg=128 % 8 == 0)
  int bid = (bid0 & 7) * 16 + (bid0 >> 3);
  int b = bid >> 5;
  int rb = (bid & 31) << 5;
  int t = threadIdx.x;
  int wid = t >> 6, lane = t & 63;

  if (t < 512) {
    int r = t >> 4, sg = t & 15;
    adjmsh[r][sg] = adjm[(size_t)(b * NN + rb + r) * 16 + sg];
  }
  // MLP piecewise-linear analysis: f(d)=A*d+B on d>=0 if no pos breakpoint
  if (t < NH) {
    float w1h = w1[t], b1h = b1[t], w2h = w2[t];
    bool bp = (w1h != 0.f) && (b1h != 0.f) && ((b1h > 0.f) != (w1h > 0.f));
    bool act = (w1h + b1h) > 0.f;
    float cA = act ? w2h * w1h : 0.f;
    float cB = act ? w2h * b1h : 0.f;
    float nbp = bp ? 1.f : 0.f;
#pragma unroll
    for (int off = 16; off >= 1; off >>= 1) {
      cA += __shfl_xor(cA, off);
      cB += __shfl_xor(cB, off);
      nbp += __shfl_xor(nbp, off);
    }
    if (t == 0) {
      segsh[0] = (nbp == 0.f) ? 1.f : 0.f;
      segsh[1] = cA;
      segsh[2] = cB + b2[0];
    }
  }
  mzs[t] = mz[b * NN + t];
  s2s[t] = s2g[b * NN + t];
  if (t < 32) s1s[t] = s1g[b * NN + rb + t];
  __syncthreads();

  float segF = segsh[0], segA = segsh[1], segB = segsh[2];
  float b2v = b2[0];
  for (int rr = 0; rr < 2; ++rr) {
    int row = wid * 2 + rr;  // 0..31; this wave owns this row entirely
    int ig = rb + row;
    float s1v = s1s[row];
    float mzi = mzs[ig];
    float e[16];
    if (segF != 0.f) {
#pragma unroll
      for (int c = 0; c < 4; ++c) {
        int j0 = c * 256 + lane * 4;
        unsigned nib =
            (unsigned)(adjmsh[row][c * 4 + (lane >> 4)] >> ((lane & 15) * 4)) &
            0xFu;
        f32x4 mzv = *(const f32x4*)(mzs + j0);
        f32x4 s2v = *(const f32x4*)(s2s + j0);
#pragma unroll
        for (int u = 0; u < 4; ++u) {
          float dd = fabsf(mzi - mzv[u]);
          float d = (ig == 0 || (j0 + u) == 0) ? 0.f : dd;
          float s = s1v + s2v[u];
          s = fmaxf(s, 0.f) + ALPHA * fminf(s, 0.f);
          float ee = s + fmaf(d, segA, segB);
          e[c * 4 + u] = (nib & (1u << u)) ? ee : NEGINF;
        }
      }
    } else {
#pragma unroll
      for (int c = 0; c < 4; ++c) {
        int j0 = c * 256 + lane * 4;
        unsigned nib =
            (unsigned)(adjmsh[row][c * 4 + (lane >> 4)] >> ((lane & 15) * 4)) &
            0xFu;
        f32x4 mzv = *(const f32x4*)(mzs + j0);
        f32x4 s2v = *(const f32x4*)(s2s + j0);
        float d[4], acc[4];
#pragma unroll
        for (int u = 0; u < 4; ++u) {
          float dd = fabsf(mzi - mzv[u]);
          d[u] = (ig == 0 || (j0 + u) == 0) ? 0.f : dd;
          acc[u] = b2v;
        }
#pragma unroll 1
        for (int hh = 0; hh < NH; ++hh) {
          float w1h = w1[hh], b1h = b1[hh], w2h = w2[hh];
#pragma unroll
          for (int u = 0; u < 4; ++u)
            acc[u] += fmaxf(d[u] * w1h + b1h, 0.f) * w2h;
        }
#pragma unroll
        for (int u = 0; u < 4; ++u) {
          float s = s1v + s2v[u];
          s = s > 0.f ? s : ALPHA * s;
          e[c * 4 + u] = (nib & (1u << u)) ? (s + acc[u]) : NEGINF;
        }
      }
    }
    float m = -3.0e38f;
#pragma unroll
    for (int q = 0; q < 16; ++q) m = fmaxf(m, e[q]);
#pragma unroll
    for (int off = 32; off >= 1; off >>= 1) m = fmaxf(m, __shfl_xor(m, off));
    float sum = 0.f;
#pragma unroll
    for (int q = 0; q < 16; ++q) {
      e[q] = __expf(e[q] - m);
      sum += e[q];
    }
#pragma unroll
    for (int off = 32; off >= 1; off >>= 1) sum += __shfl_xor(sum, off);
#pragma unroll
    for (int c = 0; c < 4; ++c) {
      u16x4 pk = {f2bf(e[c * 4 + 0]), f2bf(e[c * 4 + 1]),
                  f2bf(e[c * 4 + 2]), f2bf(e[c * 4 + 3])};
      int byteoff = row * 2048 + ((512 * c + 8 * lane) ^ ((row & 7) << 4));
      *(u16x4*)((char*)Pb + byteoff) = pk;
    }
    if (lane == 0) rinv[row] = 1.0f / sum;
  }
  __syncthreads();

  // PV: D[i][f] = sum_j P[i][j]*Wh[j][f]; per wave: 16 f-cols, 2 row-tiles
  {
    int fb = wid * 16;
    int fl = lane & 15, kg = lane >> 4;
    const unsigned short* whb = WhP + (((size_t)b) << 7) * NF * 8;
    f32x4 acc0 = {0.f, 0.f, 0.f, 0.f}, acc1 = {0.f, 0.f, 0.f, 0.f};
    int abase = fl * 2048;
#pragma unroll 8
    for (int ks = 0; ks < 32; ++ks) {
      int k0 = ks * 32;
      int kc = ks * 4 + kg;
      short8 bf = *(const short8*)(whb + (size_t)((kc * NF) + fb + fl) * 8);
      int aoff = (2 * (k0 + kg * 8)) ^ ((fl & 7) << 4);
      short8 af0 = *(const short8*)((const char*)Pb + abase + aoff);
      short8 af1 = *(const short8*)((const char*)Pb + abase + 32768 + aoff);
      acc0 = __builtin_amdgcn_mfma_f32_16x16x32_bf16(af0, bf, acc0, 0, 0, 0);
      acc1 = __builtin_amdgcn_mfma_f32_16x16x32_bf16(af1, bf, acc1, 0, 0, 0);
    }
#pragma unroll
    for (int r = 0; r < 4; ++r) {
      int il0 = (lane >> 4) * 4 + r;   // rows 0-15 tile
      int il1 = il0 + 16;              // rows 16-31 tile
      float x0 = acc0[r] * rinv[il0];
      float x1 = acc1[r] * rinv[il1];
      x0 = x0 > 0.f ? x0 : (__expf(x0) - 1.f);
      x1 = x1 > 0.f ? x1 : (__expf(x1) - 1.f);
      out[(size_t)(b * NN + rb + il0) * NF + fb + fl] = x0;
      out[(size_t)(b * NN + rb + il1) * NF + fb + fl] = x1;
    }
  }
}

extern "C" void kernel_launch(void* const* d_in, const int* in_sizes, int n_in,
                              void* d_out, int out_size, void* d_ws, size_t ws_size,
                              hipStream_t stream) {
  const float* h   = (const float*)d_in[0];
  const float* mz  = (const float*)d_in[1];
  const float* W   = (const float*)d_in[2];
  const float* a   = (const float*)d_in[3];
  const float* w1  = (const float*)d_in[4];
  const float* b1  = (const float*)d_in[5];
  const float* w2  = (const float*)d_in[6];
  const float* b2  = (const float*)d_in[7];
  const int*   adj = (const int*)d_in[8];
  float* out = (float*)d_out;

  unsigned short* WTp = (unsigned short*)d_ws;            // 256*256 bf16 = 128KB
  unsigned short* WhP = WTp + 65536;                      // 4*1024*256 bf16 = 2MB
  float* wa1 = (float*)(WhP + (size_t)NB * NN * NF);
  float* wa2 = wa1 + 256;
  float* s1g = wa2 + 256;
  float* s2g = s1g + NB * NN;
  unsigned long long* adjm = (unsigned long long*)(s2g + NB * NN);  // 512KB

  prep_kernel<<<dim3(256), dim3(256), 0, stream>>>(W, a, wa1, wa2, WTp);
  wh_kernel<<<dim3(256), dim3(512), 0, stream>>>(h, WTp, wa1, wa2, adj, WhP,
                                                 s1g, s2g, adjm);
  attn_kernel<<<dim3(128), dim3(1024), 0, stream>>>(mz, adjm, WhP, w1, b1, w2,
                                                    b2, s1g, s2g, out);
}

// Round 9
// 29.896 us; speedup vs baseline: 1.1903x; 1.1903x over previous
//
#include <hip/hip_runtime.h>
#include <hip/hip_bf16.h>

#define ALPHA 0.2f
#define NEGINF -9000000000000000.0f

typedef __attribute__((ext_vector_type(8))) short short8;
typedef __attribute__((ext_vector_type(4))) float f32x4;
typedef __attribute__((ext_vector_type(4))) int i32x4;
typedef __attribute__((ext_vector_type(4))) unsigned short u16x4;

static constexpr int NB = 4, NN = 1024, NF = 256, NH = 32;

__device__ __forceinline__ unsigned short f2bf(float x) {
  union { float f; unsigned u; } v; v.f = x;
  unsigned r = v.u + 0x7fffu + ((v.u >> 16) & 1u);
  return (unsigned short)(r >> 16);
}

// ---- Kernel A: wa1 = W@a1, wa2 = W@a2, W transpose-packed bf16 ----
// WTp layout: 16B chunk (kc, f) holds W[kc*8+s][f], s=0..7 (B-frag = 16B/lane)
__global__ __launch_bounds__(256) void prep_kernel(
    const float* __restrict__ W, const float* __restrict__ a,
    float* __restrict__ wa1, float* __restrict__ wa2,
    unsigned short* __restrict__ WTp) {
  int k = blockIdx.x;     // 0..255 (row of W)
  int t = threadIdx.x;    // 0..255 (col of W)
  float w = W[k * NF + t];
  WTp[(((k >> 3) * NF) + t) * 8 + (k & 7)] = f2bf(w);
  float p1 = w * a[t];
  float p2 = w * a[NF + t];
#pragma unroll
  for (int off = 32; off >= 1; off >>= 1) {
    p1 += __shfl_xor(p1, off);
    p2 += __shfl_xor(p2, off);
  }
  __shared__ float r1[4], r2[4];
  if ((t & 63) == 0) { r1[t >> 6] = p1; r2[t >> 6] = p2; }
  __syncthreads();
  if (t == 0) {
    wa1[k] = r1[0] + r1[1] + r1[2] + r1[3];
    wa2[k] = r2[0] + r2[1] + r2[2] + r2[3];
  }
}

// ---- Kernel B: Wh = h@W (bf16 MFMA, packed for PV B-frags) + s1/s2 ----
// WhP layout per batch: 16B chunk (jc, f) holds Wh[jc*8+s][f]
__global__ __launch_bounds__(512) void wh_kernel(
    const float* __restrict__ h, const unsigned short* __restrict__ WTp,
    const float* __restrict__ wa1, const float* __restrict__ wa2,
    unsigned short* __restrict__ WhP, float* __restrict__ s1g,
    float* __restrict__ s2g) {
  __shared__ unsigned short hs[16 * 256];  // 8KB, XOR-swizzled
  int bid = blockIdx.x;
  int b = bid >> 6;
  int rb = (bid & 63) << 4;  // 16-row tile base within batch
  int t = threadIdx.x;
  {
    int row = t >> 5, c0 = (t & 31) * 8;
    const float* src = h + (size_t)(b * NN + rb + row) * NF + c0;
    f32x4 v0 = *(const f32x4*)src;
    f32x4 v1 = *(const f32x4*)(src + 4);
    unsigned short tmp[8] = {f2bf(v0.x), f2bf(v0.y), f2bf(v0.z), f2bf(v0.w),
                             f2bf(v1.x), f2bf(v1.y), f2bf(v1.z), f2bf(v1.w)};
    int off = row * 512 + ((c0 * 2) ^ ((row & 7) << 4));
    *(short8*)((char*)hs + off) = *(const short8*)tmp;
    f32x4 a10 = *(const f32x4*)(wa1 + c0);
    f32x4 a11 = *(const f32x4*)(wa1 + c0 + 4);
    f32x4 a20 = *(const f32x4*)(wa2 + c0);
    f32x4 a21 = *(const f32x4*)(wa2 + c0 + 4);
    float d1 = v0.x * a10.x + v0.y * a10.y + v0.z * a10.z + v0.w * a10.w +
               v1.x * a11.x + v1.y * a11.y + v1.z * a11.z + v1.w * a11.w;
    float d2 = v0.x * a20.x + v0.y * a20.y + v0.z * a20.z + v0.w * a20.w +
               v1.x * a21.x + v1.y * a21.y + v1.z * a21.z + v1.w * a21.w;
#pragma unroll
    for (int off2 = 16; off2 >= 1; off2 >>= 1) {
      d1 += __shfl_xor(d1, off2);
      d2 += __shfl_xor(d2, off2);
    }
    if ((t & 31) == 0) {
      s1g[b * NN + rb + row] = d1;
      s2g[b * NN + rb + row] = d2;
    }
  }
  __syncthreads();
  int wid = t >> 6, lane = t & 63;
  int fb = wid * 32;
  int rowa = lane & 15, kg = lane >> 4;
  f32x4 acc0 = {0.f, 0.f, 0.f, 0.f}, acc1 = {0.f, 0.f, 0.f, 0.f};
#pragma unroll
  for (int ks = 0; ks < 8; ++ks) {
    int k0 = ks * 32;
    short8 af = *(const short8*)((const char*)hs + rowa * 512 +
                                 ((2 * (k0 + kg * 8)) ^ ((rowa & 7) << 4)));
    int kc = ks * 4 + kg;
    short8 bf0 = *(const short8*)(WTp + ((kc * NF) + fb + (lane & 15)) * 8);
    short8 bf1 = *(const short8*)(WTp + ((kc * NF) + fb + 16 + (lane & 15)) * 8);
    acc0 = __builtin_amdgcn_mfma_f32_16x16x32_bf16(af, bf0, acc0, 0, 0, 0);
    acc1 = __builtin_amdgcn_mfma_f32_16x16x32_bf16(af, bf1, acc1, 0, 0, 0);
  }
#pragma unroll
  for (int r = 0; r < 4; ++r) {
    int jl = (lane >> 4) * 4 + r;  // C/D layout: row=(lane>>4)*4+reg
    int j = rb + jl;
    int base = ((b << 7) + (j >> 3)) * NF;
    WhP[(size_t)(base + fb + (lane & 15)) * 8 + (j & 7)] = f2bf(acc0[r]);
    WhP[(size_t)(base + fb + 16 + (lane & 15)) * 8 + (j & 7)] = f2bf(acc1[r]);
  }
}

// ---- Kernel C: flash-style chunked scores+softmax+PV, online rescale ----
// 256 blocks x 512 threads, 16 rows/block. j-columns processed in 4 chunks
// of 256; chunk c+1's adj HBM stream overlaps chunk c's scores+PV compute.
__global__ __launch_bounds__(512) void attn_kernel(
    const float* __restrict__ mz, const int* __restrict__ adj,
    const unsigned short* __restrict__ WhP,
    const float* __restrict__ w1, const float* __restrict__ b1,
    const float* __restrict__ w2, const float* __restrict__ b2,
    const float* __restrict__ s1g, const float* __restrict__ s2g,
    float* __restrict__ out) {
  __shared__ unsigned short Pb[2][16 * 256];  // 2x8KB double-buffered bf16 P
  __shared__ float fsc[2][16];                // per-chunk rescale factors
  __shared__ float mzs[1024];
  __shared__ float s2s[1024];
  __shared__ float s1s[16];
  __shared__ float rinv[16];
  __shared__ float segsh[3];

  int bid0 = blockIdx.x;
  // XCD-aware bijective swizzle (nwg=256 % 8 == 0)
  int bid = (bid0 & 7) * 32 + (bid0 >> 3);
  int b = bid >> 6;
  int rb = (bid & 63) << 4;
  int t = threadIdx.x;
  int wid = t >> 6, lane = t & 63;
  int r0 = wid * 2, r1 = r0 + 1;  // rows owned by this wave
  const int* adjb = adj + ((size_t)(b * NN + rb)) * NN;

  // prefetch chunk 0 adj (in flight during staging below)
  i32x4 avA[2], avB[2];
  avA[0] = *(const i32x4*)(adjb + (size_t)r0 * NN + lane * 4);
  avA[1] = *(const i32x4*)(adjb + (size_t)r1 * NN + lane * 4);
  avB[0] = avA[0]; avB[1] = avA[1];

  // MLP piecewise-linear analysis: f(d)=A*d+B on d>=0 if no pos breakpoint
  if (t < NH) {
    float w1h = w1[t], b1h = b1[t], w2h = w2[t];
    bool bp = (w1h != 0.f) && (b1h != 0.f) && ((b1h > 0.f) != (w1h > 0.f));
    bool act = (w1h + b1h) > 0.f;
    float cA = act ? w2h * w1h : 0.f;
    float cB = act ? w2h * b1h : 0.f;
    float nbp = bp ? 1.f : 0.f;
#pragma unroll
    for (int off = 16; off >= 1; off >>= 1) {
      cA += __shfl_xor(cA, off);
      cB += __shfl_xor(cB, off);
      nbp += __shfl_xor(nbp, off);
    }
    if (t == 0) {
      segsh[0] = (nbp == 0.f) ? 1.f : 0.f;
      segsh[1] = cA;
      segsh[2] = cB + b2[0];
    }
  }
  for (int i = t; i < NN; i += 512) {
    mzs[i] = mz[b * NN + i];
    s2s[i] = s2g[b * NN + i];
  }
  if (t < 16) s1s[t] = s1g[b * NN + rb + t];
  __syncthreads();

  float segF = segsh[0], segA = segsh[1], segB = segsh[2];
  float b2v = b2[0];
  float mrun[2] = {-3.0e38f, -3.0e38f};
  float lrun[2] = {0.f, 0.f};
  int fb = wid * 32;
  int rowa = lane & 15, kg = lane >> 4;
  const unsigned short* whb = WhP + (((size_t)b) << 7) * NF * 8;
  f32x4 acc0 = {0.f, 0.f, 0.f, 0.f}, acc1 = {0.f, 0.f, 0.f, 0.f};

  for (int c = 0; c < 4; ++c) {
    // issue next chunk's adj loads (hide HBM latency under compute)
    if (c < 3) {
      avB[0] = *(const i32x4*)(adjb + (size_t)r0 * NN + (c + 1) * 256 + lane * 4);
      avB[1] = *(const i32x4*)(adjb + (size_t)r1 * NN + (c + 1) * 256 + lane * 4);
    }
    // scores + online softmax for this chunk (wave owns rows r0, r1)
#pragma unroll
    for (int rr = 0; rr < 2; ++rr) {
      int row = wid * 2 + rr;
      int ig = rb + row;
      float s1v = s1s[row];
      float mzi = mzs[ig];
      int j0 = c * 256 + lane * 4;
      i32x4 av = avA[rr];
      f32x4 mzv = *(const f32x4*)(mzs + j0);
      f32x4 s2v = *(const f32x4*)(s2s + j0);
      float e[4];
      if (segF != 0.f) {
#pragma unroll
        for (int u = 0; u < 4; ++u) {
          float dd = fabsf(mzi - mzv[u]);
          float d = (ig == 0 || (j0 + u) == 0) ? 0.f : dd;
          float s = s1v + s2v[u];
          s = fmaxf(s, 0.f) + ALPHA * fminf(s, 0.f);
          float ee = s + fmaf(d, segA, segB);
          e[u] = (av[u] > 0) ? ee : NEGINF;
        }
      } else {
        float d[4], acc[4];
#pragma unroll
        for (int u = 0; u < 4; ++u) {
          float dd = fabsf(mzi - mzv[u]);
          d[u] = (ig == 0 || (j0 + u) == 0) ? 0.f : dd;
          acc[u] = b2v;
        }
#pragma unroll 1
        for (int hh = 0; hh < NH; ++hh) {
          float w1h = w1[hh], b1h = b1[hh], w2h = w2[hh];
#pragma unroll
          for (int u = 0; u < 4; ++u)
            acc[u] += fmaxf(d[u] * w1h + b1h, 0.f) * w2h;
        }
#pragma unroll
        for (int u = 0; u < 4; ++u) {
          float s = s1v + s2v[u];
          s = s > 0.f ? s : ALPHA * s;
          e[u] = (av[u] > 0) ? (s + acc[u]) : NEGINF;
        }
      }
      float cmax = fmaxf(fmaxf(e[0], e[1]), fmaxf(e[2], e[3]));
#pragma unroll
      for (int off = 32; off >= 1; off >>= 1)
        cmax = fmaxf(cmax, __shfl_xor(cmax, off));
      float mnew = fmaxf(mrun[rr], cmax);
      float fr = __expf(mrun[rr] - mnew);
      mrun[rr] = mnew;
      float csum = 0.f;
#pragma unroll
      for (int u = 0; u < 4; ++u) {
        e[u] = __expf(e[u] - mnew);
        csum += e[u];
      }
#pragma unroll
      for (int off = 32; off >= 1; off >>= 1) csum += __shfl_xor(csum, off);
      lrun[rr] = lrun[rr] * fr + csum;
      u16x4 pk = {f2bf(e[0]), f2bf(e[1]), f2bf(e[2]), f2bf(e[3])};
      int byteoff = row * 512 + ((8 * lane) ^ ((row & 7) << 4));
      *(u16x4*)((char*)Pb[c & 1] + byteoff) = pk;
      if (lane == 0) fsc[c & 1][row] = fr;
    }
    avA[0] = avB[0];
    avA[1] = avB[1];
    __syncthreads();  // P chunk + fsc visible; Pb[(c+1)&1] free to overwrite

    // rescale accumulators, then partial PV over this chunk's 256 j-cols
#pragma unroll
    for (int r = 0; r < 4; ++r) {
      float frr = fsc[c & 1][(lane >> 4) * 4 + r];
      acc0[r] *= frr;
      acc1[r] *= frr;
    }
#pragma unroll
    for (int ks = 0; ks < 8; ++ks) {
      int kc = (c * 8 + ks) * 4 + kg;
      short8 af = *(const short8*)((const char*)Pb[c & 1] + rowa * 512 +
                                   ((2 * (ks * 32 + kg * 8)) ^ ((rowa & 7) << 4)));
      short8 bf0 = *(const short8*)(whb + (size_t)((kc * NF) + fb + rowa) * 8);
      short8 bf1 = *(const short8*)(whb + (size_t)((kc * NF) + fb + 16 + rowa) * 8);
      acc0 = __builtin_amdgcn_mfma_f32_16x16x32_bf16(af, bf0, acc0, 0, 0, 0);
      acc1 = __builtin_amdgcn_mfma_f32_16x16x32_bf16(af, bf1, acc1, 0, 0, 0);
    }
  }

  if (lane == 0) {
    rinv[r0] = 1.0f / lrun[0];
    rinv[r1] = 1.0f / lrun[1];
  }
  __syncthreads();

#pragma unroll
  for (int r = 0; r < 4; ++r) {
    int il = (lane >> 4) * 4 + r;
    float inv = rinv[il];
    float x0 = acc0[r] * inv;
    float x1 = acc1[r] * inv;
    x0 = x0 > 0.f ? x0 : (__expf(x0) - 1.f);
    x1 = x1 > 0.f ? x1 : (__expf(x1) - 1.f);
    size_t ob = (size_t)(b * NN + rb + il) * NF + fb + rowa;
    out[ob] = x0;
    out[ob + 16] = x1;
  }
}

extern "C" void kernel_launch(void* const* d_in, const int* in_sizes, int n_in,
                              void* d_out, int out_size, void* d_ws, size_t ws_size,
                              hipStream_t stream) {
  const float* h   = (const float*)d_in[0];
  const float* mz  = (const float*)d_in[1];
  const float* W   = (const float*)d_in[2];
  const float* a   = (const float*)d_in[3];
  const float* w1  = (const float*)d_in[4];
  const float* b1  = (const float*)d_in[5];
  const float* w2  = (const float*)d_in[6];
  const float* b2  = (const float*)d_in[7];
  const int*   adj = (const int*)d_in[8];
  float* out = (float*)d_out;

  unsigned short* WTp = (unsigned short*)d_ws;            // 256*256 bf16 = 128KB
  unsigned short* WhP = WTp + 65536;                      // 4*1024*256 bf16 = 2MB
  float* wa1 = (float*)(WhP + (size_t)NB * NN * NF);
  float* wa2 = wa1 + 256;
  float* s1g = wa2 + 256;
  float* s2g = s1g + NB * NN;

  prep_kernel<<<dim3(256), dim3(256), 0, stream>>>(W, a, wa1, wa2, WTp);
  wh_kernel<<<dim3(256), dim3(512), 0, stream>>>(h, WTp, wa1, wa2, WhP, s1g, s2g);
  attn_kernel<<<dim3(256), dim3(512), 0, stream>>>(mz, adj, WhP, w1, b1, w2,
                                                   b2, s1g, s2g, out);
}

// Round 10
// 27.311 us; speedup vs baseline: 1.3029x; 1.0946x over previous
//
#include <hip/hip_runtime.h>
#include <hip/hip_bf16.h>

#define ALPHA 0.2f
#define NEGINF -9000000000000000.0f

typedef __attribute__((ext_vector_type(8))) short short8;
typedef __attribute__((ext_vector_type(4))) float f32x4;
typedef __attribute__((ext_vector_type(4))) int i32x4;
typedef __attribute__((ext_vector_type(4))) unsigned short u16x4;

static constexpr int NB = 4, NN = 1024, NF = 256, NH = 32;

__device__ __forceinline__ unsigned short f2bf(float x) {
  union { float f; unsigned u; } v; v.f = x;
  unsigned r = v.u + 0x7fffu + ((v.u >> 16) & 1u);
  return (unsigned short)(r >> 16);
}

// ---- Kernel A: W pack + wa1/wa2 + adj->bitmask (adj stream hides under W) --
// WTp: 16B chunk (kc, f) holds W[kc*8+s][f].  adjm[grow*16+seg] = bits of
// adj[grow][seg*64..seg*64+63] > 0.  Block k: W row k + adj rows k*16..k*16+15.
__global__ __launch_bounds__(256) void prep_kernel(
    const float* __restrict__ W, const float* __restrict__ a,
    const int* __restrict__ adj, float* __restrict__ wa1,
    float* __restrict__ wa2, unsigned short* __restrict__ WTp,
    unsigned long long* __restrict__ adjm) {
  int k = blockIdx.x;     // 0..255
  int t = threadIdx.x;    // 0..255
  // issue adj loads FIRST (64KB/block, coalesced); they land during W phase
  const int* ap = adj + ((size_t)(k * 16 + (t >> 4))) * NN + (t & 15) * 64;
  i32x4 av[16];
#pragma unroll
  for (int i = 0; i < 16; ++i) av[i] = *(const i32x4*)(ap + i * 4);

  float w = W[k * NF + t];
  WTp[(((k >> 3) * NF) + t) * 8 + (k & 7)] = f2bf(w);
  float p1 = w * a[t];
  float p2 = w * a[NF + t];
#pragma unroll
  for (int off = 32; off >= 1; off >>= 1) {
    p1 += __shfl_xor(p1, off);
    p2 += __shfl_xor(p2, off);
  }
  __shared__ float r1[4], r2[4];
  if ((t & 63) == 0) { r1[t >> 6] = p1; r2[t >> 6] = p2; }
  __syncthreads();
  if (t == 0) {
    wa1[k] = r1[0] + r1[1] + r1[2] + r1[3];
    wa2[k] = r2[0] + r2[1] + r2[2] + r2[3];
  }

  unsigned long long m = 0ull;
#pragma unroll
  for (int i = 0; i < 16; ++i)
#pragma unroll
    for (int u = 0; u < 4; ++u)
      m |= (unsigned long long)(av[i][u] > 0) << (i * 4 + u);
  adjm[(size_t)k * 256 + t] = m;   // == grow*16 + seg
}

// ---- Kernel B: Wh = h@W (bf16 MFMA, packed for PV B-frags) + s1/s2 ----
// WhP layout per batch: 16B chunk (jc, f) holds Wh[jc*8+s][f]
__global__ __launch_bounds__(512) void wh_kernel(
    const float* __restrict__ h, const unsigned short* __restrict__ WTp,
    const float* __restrict__ wa1, const float* __restrict__ wa2,
    unsigned short* __restrict__ WhP, float* __restrict__ s1g,
    float* __restrict__ s2g) {
  __shared__ unsigned short hs[16 * 256];  // 8KB, XOR-swizzled
  int bid = blockIdx.x;
  int b = bid >> 6;
  int rb = (bid & 63) << 4;  // 16-row tile base within batch
  int t = threadIdx.x;
  {
    int row = t >> 5, c0 = (t & 31) * 8;
    const float* src = h + (size_t)(b * NN + rb + row) * NF + c0;
    f32x4 v0 = *(const f32x4*)src;
    f32x4 v1 = *(const f32x4*)(src + 4);
    unsigned short tmp[8] = {f2bf(v0.x), f2bf(v0.y), f2bf(v0.z), f2bf(v0.w),
                             f2bf(v1.x), f2bf(v1.y), f2bf(v1.z), f2bf(v1.w)};
    int off = row * 512 + ((c0 * 2) ^ ((row & 7) << 4));
    *(short8*)((char*)hs + off) = *(const short8*)tmp;
    f32x4 a10 = *(const f32x4*)(wa1 + c0);
    f32x4 a11 = *(const f32x4*)(wa1 + c0 + 4);
    f32x4 a20 = *(const f32x4*)(wa2 + c0);
    f32x4 a21 = *(const f32x4*)(wa2 + c0 + 4);
    float d1 = v0.x * a10.x + v0.y * a10.y + v0.z * a10.z + v0.w * a10.w +
               v1.x * a11.x + v1.y * a11.y + v1.z * a11.z + v1.w * a11.w;
    float d2 = v0.x * a20.x + v0.y * a20.y + v0.z * a20.z + v0.w * a20.w +
               v1.x * a21.x + v1.y * a21.y + v1.z * a21.z + v1.w * a21.w;
#pragma unroll
    for (int off2 = 16; off2 >= 1; off2 >>= 1) {
      d1 += __shfl_xor(d1, off2);
      d2 += __shfl_xor(d2, off2);
    }
    if ((t & 31) == 0) {
      s1g[b * NN + rb + row] = d1;
      s2g[b * NN + rb + row] = d2;
    }
  }
  __syncthreads();
  int wid = t >> 6, lane = t & 63;
  int fb = wid * 32;
  int rowa = lane & 15, kg = lane >> 4;
  f32x4 acc0 = {0.f, 0.f, 0.f, 0.f}, acc1 = {0.f, 0.f, 0.f, 0.f};
#pragma unroll
  for (int ks = 0; ks < 8; ++ks) {
    int k0 = ks * 32;
    short8 af = *(const short8*)((const char*)hs + rowa * 512 +
                                 ((2 * (k0 + kg * 8)) ^ ((rowa & 7) << 4)));
    int kc = ks * 4 + kg;
    short8 bf0 = *(const short8*)(WTp + ((kc * NF) + fb + (lane & 15)) * 8);
    short8 bf1 = *(const short8*)(WTp + ((kc * NF) + fb + 16 + (lane & 15)) * 8);
    acc0 = __builtin_amdgcn_mfma_f32_16x16x32_bf16(af, bf0, acc0, 0, 0, 0);
    acc1 = __builtin_amdgcn_mfma_f32_16x16x32_bf16(af, bf1, acc1, 0, 0, 0);
  }
#pragma unroll
  for (int r = 0; r < 4; ++r) {
    int jl = (lane >> 4) * 4 + r;  // C/D layout: row=(lane>>4)*4+reg
    int j = rb + jl;
    int base = ((b << 7) + (j >> 3)) * NF;
    WhP[(size_t)(base + fb + (lane & 15)) * 8 + (j & 7)] = f2bf(acc0[r]);
    WhP[(size_t)(base + fb + 16 + (lane & 15)) * 8 + (j & 7)] = f2bf(acc1[r]);
  }
}

// ---- Kernel C: scores + softmax + PV + ELU (R7 structure, mask-fed) ----
// 128 blocks x 1024 threads (16 waves), 32 rows per block; adjacency from
// the packed bitmask (4KB/block, L2) instead of 128KB int32 from HBM.
__global__ __launch_bounds__(1024) void attn_kernel(
    const float* __restrict__ mz, const unsigned long long* __restrict__ adjm,
    const unsigned short* __restrict__ WhP,
    const float* __restrict__ w1, const float* __restrict__ b1,
    const float* __restrict__ w2, const float* __restrict__ b2,
    const float* __restrict__ s1g, const float* __restrict__ s2g,
    float* __restrict__ out) {
  __shared__ unsigned short Pb[32 * 1024];  // 64KB XOR-swizzled bf16 P
  __shared__ unsigned long long adjmsh[32][16];  // 4KB bitmask
  __shared__ float mzs[1024];
  __shared__ float s2s[1024];
  __shared__ float s1s[32];
  __shared__ float rinv[32];
  __shared__ float segsh[3];

  int bid0 = blockIdx.x;  // 0..127
  // XCD-aware bijective swizzle (nwg=128 % 8 == 0)
  int bid = (bid0 & 7) * 16 + (bid0 >> 3);
  int b = bid >> 5;
  int rb = (bid & 31) << 5;
  int t = threadIdx.x;
  int wid = t >> 6, lane = t & 63;

  if (t < 512) {
    int r = t >> 4, sg = t & 15;
    adjmsh[r][sg] = adjm[(size_t)(b * NN + rb + r) * 16 + sg];
  }
  // MLP piecewise-linear analysis: f(d)=A*d+B on d>=0 if no pos breakpoint
  if (t < NH) {
    float w1h = w1[t], b1h = b1[t], w2h = w2[t];
    bool bp = (w1h != 0.f) && (b1h != 0.f) && ((b1h > 0.f) != (w1h > 0.f));
    bool act = (w1h + b1h) > 0.f;
    float cA = act ? w2h * w1h : 0.f;
    float cB = act ? w2h * b1h : 0.f;
    float nbp = bp ? 1.f : 0.f;
#pragma unroll
    for (int off = 16; off >= 1; off >>= 1) {
      cA += __shfl_xor(cA, off);
      cB += __shfl_xor(cB, off);
      nbp += __shfl_xor(nbp, off);
    }
    if (t == 0) {
      segsh[0] = (nbp == 0.f) ? 1.f : 0.f;
      segsh[1] = cA;
      segsh[2] = cB + b2[0];
    }
  }
  mzs[t] = mz[b * NN + t];
  s2s[t] = s2g[b * NN + t];
  if (t < 32) s1s[t] = s1g[b * NN + rb + t];
  __syncthreads();

  float segF = segsh[0], segA = segsh[1], segB = segsh[2];
  float b2v = b2[0];
  for (int rr = 0; rr < 2; ++rr) {
    int row = wid * 2 + rr;  // 0..31; this wave owns this row entirely
    int ig = rb + row;
    float s1v = s1s[row];
    float mzi = mzs[ig];
    float e[16];
    if (segF != 0.f) {
#pragma unroll
      for (int c = 0; c < 4; ++c) {
        int j0 = c * 256 + lane * 4;
        unsigned nib =
            (unsigned)(adjmsh[row][c * 4 + (lane >> 4)] >> ((lane & 15) * 4)) &
            0xFu;
        f32x4 mzv = *(const f32x4*)(mzs + j0);
        f32x4 s2v = *(const f32x4*)(s2s + j0);
#pragma unroll
        for (int u = 0; u < 4; ++u) {
          float dd = fabsf(mzi - mzv[u]);
          float d = (ig == 0 || (j0 + u) == 0) ? 0.f : dd;
          float s = s1v + s2v[u];
          s = fmaxf(s, 0.f) + ALPHA * fminf(s, 0.f);
          float ee = s + fmaf(d, segA, segB);
          e[c * 4 + u] = (nib & (1u << u)) ? ee : NEGINF;
        }
      }
    } else {
#pragma unroll
      for (int c = 0; c < 4; ++c) {
        int j0 = c * 256 + lane * 4;
        unsigned nib =
            (unsigned)(adjmsh[row][c * 4 + (lane >> 4)] >> ((lane & 15) * 4)) &
            0xFu;
        f32x4 mzv = *(const f32x4*)(mzs + j0);
        f32x4 s2v = *(const f32x4*)(s2s + j0);
        float d[4], acc[4];
#pragma unroll
        for (int u = 0; u < 4; ++u) {
          float dd = fabsf(mzi - mzv[u]);
          d[u] = (ig == 0 || (j0 + u) == 0) ? 0.f : dd;
          acc[u] = b2v;
        }
#pragma unroll 1
        for (int hh = 0; hh < NH; ++hh) {
          float w1h = w1[hh], b1h = b1[hh], w2h = w2[hh];
#pragma unroll
          for (int u = 0; u < 4; ++u)
            acc[u] += fmaxf(d[u] * w1h + b1h, 0.f) * w2h;
        }
#pragma unroll
        for (int u = 0; u < 4; ++u) {
          float s = s1v + s2v[u];
          s = s > 0.f ? s : ALPHA * s;
          e[c * 4 + u] = (nib & (1u << u)) ? (s + acc[u]) : NEGINF;
        }
      }
    }
    float m = -3.0e38f;
#pragma unroll
    for (int q = 0; q < 16; ++q) m = fmaxf(m, e[q]);
#pragma unroll
    for (int off = 32; off >= 1; off >>= 1) m = fmaxf(m, __shfl_xor(m, off));
    float sum = 0.f;
#pragma unroll
    for (int q = 0; q < 16; ++q) {
      e[q] = __expf(e[q] - m);
      sum += e[q];
    }
#pragma unroll
    for (int off = 32; off >= 1; off >>= 1) sum += __shfl_xor(sum, off);
#pragma unroll
    for (int c = 0; c < 4; ++c) {
      u16x4 pk = {f2bf(e[c * 4 + 0]), f2bf(e[c * 4 + 1]),
                  f2bf(e[c * 4 + 2]), f2bf(e[c * 4 + 3])};
      int byteoff = row * 2048 + ((512 * c + 8 * lane) ^ ((row & 7) << 4));
      *(u16x4*)((char*)Pb + byteoff) = pk;
    }
    if (lane == 0) rinv[row] = 1.0f / sum;
  }
  __syncthreads();

  // PV: D[i][f] = sum_j P[i][j]*Wh[j][f]; per wave: 16 f-cols, 2 row-tiles
  {
    int fb = wid * 16;
    int fl = lane & 15, kg = lane >> 4;
    const unsigned short* whb = WhP + (((size_t)b) << 7) * NF * 8;
    f32x4 acc0 = {0.f, 0.f, 0.f, 0.f}, acc1 = {0.f, 0.f, 0.f, 0.f};
    int abase = fl * 2048;
#pragma unroll 4
    for (int ks = 0; ks < 32; ++ks) {
      int k0 = ks * 32;
      int kc = ks * 4 + kg;
      short8 bf = *(const short8*)(whb + (size_t)((kc * NF) + fb + fl) * 8);
      int aoff = (2 * (k0 + kg * 8)) ^ ((fl & 7) << 4);
      short8 af0 = *(const short8*)((const char*)Pb + abase + aoff);
      short8 af1 = *(const short8*)((const char*)Pb + abase + 32768 + aoff);
      acc0 = __builtin_amdgcn_mfma_f32_16x16x32_bf16(af0, bf, acc0, 0, 0, 0);
      acc1 = __builtin_amdgcn_mfma_f32_16x16x32_bf16(af1, bf, acc1, 0, 0, 0);
    }
#pragma unroll
    for (int r = 0; r < 4; ++r) {
      int il0 = (lane >> 4) * 4 + r;   // rows 0-15 tile
      int il1 = il0 + 16;              // rows 16-31 tile
      float x0 = acc0[r] * rinv[il0];
      float x1 = acc1[r] * rinv[il1];
      x0 = x0 > 0.f ? x0 : (__expf(x0) - 1.f);
      x1 = x1 > 0.f ? x1 : (__expf(x1) - 1.f);
      out[(size_t)(b * NN + rb + il0) * NF + fb + fl] = x0;
      out[(size_t)(b * NN + rb + il1) * NF + fb + fl] = x1;
    }
  }
}

extern "C" void kernel_launch(void* const* d_in, const int* in_sizes, int n_in,
                              void* d_out, int out_size, void* d_ws, size_t ws_size,
                              hipStream_t stream) {
  const float* h   = (const float*)d_in[0];
  const float* mz  = (const float*)d_in[1];
  const float* W   = (const float*)d_in[2];
  const float* a   = (const float*)d_in[3];
  const float* w1  = (const float*)d_in[4];
  const float* b1  = (const float*)d_in[5];
  const float* w2  = (const float*)d_in[6];
  const float* b2  = (const float*)d_in[7];
  const int*   adj = (const int*)d_in[8];
  float* out = (float*)d_out;

  unsigned short* WTp = (unsigned short*)d_ws;            // 256*256 bf16 = 128KB
  unsigned short* WhP = WTp + 65536;                      // 4*1024*256 bf16 = 2MB
  float* wa1 = (float*)(WhP + (size_t)NB * NN * NF);
  float* wa2 = wa1 + 256;
  float* s1g = wa2 + 256;
  float* s2g = s1g + NB * NN;
  unsigned long long* adjm = (unsigned long long*)(s2g + NB * NN);  // 512KB

  prep_kernel<<<dim3(256), dim3(256), 0, stream>>>(W, a, adj, wa1, wa2, WTp,
                                                   adjm);
  wh_kernel<<<dim3(256), dim3(512), 0, stream>>>(h, WTp, wa1, wa2, WhP, s1g, s2g);
  attn_kernel<<<dim3(128), dim3(1024), 0, stream>>>(mz, adjm, WhP, w1, b1, w2,
                                                    b2, s1g, s2g, out);
}